// Round 1
// 789.320 us; speedup vs baseline: 1.0796x; 1.0796x over previous
//
#include <hip/hip_runtime.h>
#include <math.h>

#define EPSF 1e-5f

constexpr int Sn = 5, Bn = 8, Hin = 512, Win = 512, Cn = 64;
constexpr int HO = 257, WO = 257;
constexpr int HW = HO * WO;           // 66049  (== 1 mod 4)
constexpr int NPIX = Bn * HW;         // 528392
constexpr int TOTPIX = Sn * NPIX;     // 2641960

// Workspace layout per scale (floats):
//   [0,64)          : sorted breakpoints tS[64]
//   [64, 64+64*66*2): alpha/beta as float2 ab[o][r], row stride 66 (r in [0,65))
constexpr int WSF = 64 + Cn * 66 * 2;  // 8512 floats per scale

// ---------------------------------------------------------------------------
// Precompute: piecewise-linear table of the scalar->64ch MLP (unchanged).
// ---------------------------------------------------------------------------
__global__ __launch_bounds__(64) void precompute_kernel(
    const float* __restrict__ w1, const float* __restrict__ w2,
    const float* __restrict__ g1, const float* __restrict__ b1,
    const float* __restrict__ m1, const float* __restrict__ v1,
    const float* __restrict__ g2, const float* __restrict__ b2,
    const float* __restrict__ m2, const float* __restrict__ v2,
    float* __restrict__ ws) {
    int s = blockIdx.x;
    int c = threadIdx.x;
    __shared__ float sa1[Cn], st1[Cn], stc[Cn], stS[Cn];
    __shared__ int   scS[Cn];

    int idx = s * Cn + c;
    float sc1 = g1[idx] / sqrtf(v1[idx] + EPSF);
    float a1  = sc1 * w1[idx];                 // w1 shape (S,C,1)
    float t1  = b1[idx] - m1[idx] * sc1;
    sa1[c] = a1;
    st1[c] = t1;
    float tc = (a1 != 0.f) ? (-t1 / a1) : INFINITY;
    stc[c] = tc;
    __syncthreads();

    int rk = 0;
    for (int c2 = 0; c2 < Cn; c2++) {
        float t = stc[c2];
        rk += (t < tc) || (t == tc && c2 < c);
    }
    stS[rk] = tc;
    scS[rk] = c;
    __syncthreads();

    float* wss = ws + (size_t)s * WSF;
    wss[c] = stS[c];

    int o = c;
    float sc2 = g2[idx] / sqrtf(v2[idx] + EPSF);
    float t2o = b2[idx] - m2[idx] * sc2;
    const float* w2row = w2 + ((size_t)s * Cn + o) * Cn;

    float alpha = 0.f, beta = t2o;
    for (int cc = 0; cc < Cn; cc++) {
        float a = sa1[cc];
        bool act = (a < 0.f) || (a == 0.f && st1[cc] > 0.f);
        if (act) {
            float wf = sc2 * w2row[cc];
            alpha = fmaf(wf, a, alpha);
            beta  = fmaf(wf, st1[cc], beta);
        }
    }
    float2* abrow = (float2*)(wss + Cn);
    abrow[o * 66 + 0] = make_float2(alpha, beta);

    for (int r = 1; r <= Cn; r++) {
        int cc = scS[r - 1];
        float a = sa1[cc];
        if (a != 0.f) {
            float wf = sc2 * w2row[cc];
            float sgn = (a > 0.f) ? 1.f : -1.f;
            alpha = fmaf(sgn * wf, a, alpha);
            beta  = fmaf(sgn * wf, st1[cc], beta);
        }
        abrow[o * 66 + r] = make_float2(alpha, beta);
    }
}

// ---------------------------------------------------------------------------
// Fused DWT + PWL-MLP, v2: float4 P-stores via mod-4 phase shift + 3-px halo.
//   grid = (chunk, b, s); each thread owns 4 consecutive pixels of one
//   (s,b) plane and computes 7 (3 halo, bitwise-identical to neighbor's).
//   Plane stride HW == 1 (mod 4), so channel o's aligned float4 window is
//   shifted by delta_o = (-o) mod 4; values selected with STATIC indices.
// ---------------------------------------------------------------------------
constexpr int GPT = 4;                  // owned pixels per thread
constexpr int TPB = 256;
constexpr int PIXPB = TPB * GPT;        // 1024 pixels per block
constexpr int NCHUNK = (HW + PIXPB - 1) / PIXPB;  // 65

__device__ __forceinline__ float pwl(const float2 ab, float v) {
    return fmaxf(fmaf(ab.x, v, ab.y), 0.f);
}

__global__ __launch_bounds__(TPB) void fused_kernel(
    const float* __restrict__ x,
    const float* __restrict__ lp, const float* __restrict__ hp,
    const float* __restrict__ ws,
    float* __restrict__ Lout, float* __restrict__ Hout,
    float* __restrict__ Pout) {
    __shared__ float  stS[Cn];
    __shared__ float2 sab[Cn * 66];

    const int tid = threadIdx.x;
    const int b = blockIdx.y, s = blockIdx.z;
    const float* wss = ws + (size_t)s * WSF;
    if (tid < Cn) stS[tid] = wss[tid];
    const float2* abg = (const float2*)(wss + Cn);
    for (int t = tid; t < Cn * 66; t += TPB) sab[t] = abg[t];
    __syncthreads();

    const int pbase = (blockIdx.x * TPB + tid) * GPT;  // plane-local pixel idx
    if (pbase >= HW) return;

    const float l0 = lp[2 * s], l1 = lp[2 * s + 1];
    const float h0 = hp[2 * s], h1 = hp[2 * s + 1];
    const float* xb = x + (size_t)b * (Hin * Win);

    float Lv[GPT + 3];
    float Hv[GPT];
    int   lo7[GPT + 3];

    #pragma unroll
    for (int q = 0; q < GPT + 3; ++q) {
        const int px = pbase + q;
        float Lq = 0.f, Hq = 0.f;
        if (px < HW) {
            const int i = px / WO;
            const int j = px - i * WO;
            const int r0 = 2 * i - 1, r1 = 2 * i;
            const int c0 = 2 * j - 1, c1 = 2 * j;
            const float x00 = (r0 >= 0  && c0 >= 0 ) ? xb[r0 * Win + c0] : 0.f;
            const float x01 = (r0 >= 0  && c1 < Win) ? xb[r0 * Win + c1] : 0.f;
            const float x10 = (r1 < Hin && c0 >= 0 ) ? xb[r1 * Win + c0] : 0.f;
            const float x11 = (r1 < Hin && c1 < Win) ? xb[r1 * Win + c1] : 0.f;
            Lq = l0 * (l0 * x00 + l1 * x01) + l1 * (l0 * x10 + l1 * x11);
            Hq = h0 * (h0 * x00 + h1 * x01) + h1 * (h0 * x10 + h1 * x11);
        }
        Lv[q] = Lq;
        if (q < GPT) Hv[q] = Hq;
        // region = count of breakpoints < Lq (7-step binary search)
        int lo = 0, hi = Cn;
        while (lo < hi) {
            const int mid = (lo + hi) >> 1;
            if (stS[mid] < Lq) lo = mid + 1; else hi = mid;
        }
        lo7[q] = lo;
    }

    // L / H stores (scalar; 1/32 of the store traffic)
    {
        const size_t lbase = (size_t)(s * Bn + b) * HW + pbase;
        #pragma unroll
        for (int q = 0; q < GPT; ++q) {
            if (pbase + q < HW) {
                Lout[lbase + q] = Lv[q];
                Hout[lbase + q] = Hv[q];
            }
        }
    }

    float* const Pb = Pout + ((size_t)(s * Bn + b) * Cn) * HW + pbase;

    if (pbase + GPT + 3 <= HW) {
        // -------- fast path: full halo valid, all stores float4-aligned ----
        float* po = Pb;
        #pragma unroll 2
        for (int o = 0; o < Cn; o += 4, po += (size_t)4 * HW) {
            {   // o+0: delta 0, pixels q=0..3
                const float2 a0 = sab[o * 66 + lo7[0]];
                const float2 a1 = sab[o * 66 + lo7[1]];
                const float2 a2 = sab[o * 66 + lo7[2]];
                const float2 a3 = sab[o * 66 + lo7[3]];
                const float4 v = make_float4(pwl(a0, Lv[0]), pwl(a1, Lv[1]),
                                             pwl(a2, Lv[2]), pwl(a3, Lv[3]));
                *(float4*)(po) = v;
            }
            {   // o+1: delta 3, pixels q=3..6
                const float2 a0 = sab[(o + 1) * 66 + lo7[3]];
                const float2 a1 = sab[(o + 1) * 66 + lo7[4]];
                const float2 a2 = sab[(o + 1) * 66 + lo7[5]];
                const float2 a3 = sab[(o + 1) * 66 + lo7[6]];
                const float4 v = make_float4(pwl(a0, Lv[3]), pwl(a1, Lv[4]),
                                             pwl(a2, Lv[5]), pwl(a3, Lv[6]));
                *(float4*)(po + HW + 3) = v;
            }
            {   // o+2: delta 2, pixels q=2..5
                const float2 a0 = sab[(o + 2) * 66 + lo7[2]];
                const float2 a1 = sab[(o + 2) * 66 + lo7[3]];
                const float2 a2 = sab[(o + 2) * 66 + lo7[4]];
                const float2 a3 = sab[(o + 2) * 66 + lo7[5]];
                const float4 v = make_float4(pwl(a0, Lv[2]), pwl(a1, Lv[3]),
                                             pwl(a2, Lv[4]), pwl(a3, Lv[5]));
                *(float4*)(po + 2 * (size_t)HW + 2) = v;
            }
            {   // o+3: delta 1, pixels q=1..4
                const float2 a0 = sab[(o + 3) * 66 + lo7[1]];
                const float2 a1 = sab[(o + 3) * 66 + lo7[2]];
                const float2 a2 = sab[(o + 3) * 66 + lo7[3]];
                const float2 a3 = sab[(o + 3) * 66 + lo7[4]];
                const float4 v = make_float4(pwl(a0, Lv[1]), pwl(a1, Lv[2]),
                                             pwl(a2, Lv[3]), pwl(a3, Lv[4]));
                *(float4*)(po + 3 * (size_t)HW + 1) = v;
            }
        }
        // plane-head patch: pixels [0, delta_o) — only the pbase==0 thread
        if (pbase == 0) {
            float* ph = Pb;
            for (int o = 0; o < Cn; ++o, ph += HW) {
                const int d = (4 - (o & 3)) & 3;
                if (d > 0) ph[0] = pwl(sab[o * 66 + lo7[0]], Lv[0]);
                if (d > 1) ph[1] = pwl(sab[o * 66 + lo7[1]], Lv[1]);
                if (d > 2) ph[2] = pwl(sab[o * 66 + lo7[2]], Lv[2]);
            }
        }
    } else {
        // -------- slow path: plane tail, scalar bounds-checked stores ------
        #pragma unroll
        for (int q = 0; q < GPT; ++q) {
            const int px = pbase + q;
            if (px >= HW) break;
            const float Lq = Lv[q];
            const int   r  = lo7[q];
            float* Pp = Pb + q;
            #pragma unroll 8
            for (int o = 0; o < Cn; ++o) {
                Pp[(size_t)o * HW] = pwl(sab[o * 66 + r], Lq);
            }
        }
    }
}

extern "C" void kernel_launch(void* const* d_in, const int* in_sizes, int n_in,
                              void* d_out, int out_size, void* d_ws, size_t ws_size,
                              hipStream_t stream) {
    const float* x  = (const float*)d_in[0];
    const float* lp = (const float*)d_in[1];
    const float* hp = (const float*)d_in[2];
    const float* w1 = (const float*)d_in[3];
    const float* w2 = (const float*)d_in[4];
    const float* g1 = (const float*)d_in[5];
    const float* b1 = (const float*)d_in[6];
    const float* m1 = (const float*)d_in[7];
    const float* v1 = (const float*)d_in[8];
    const float* g2 = (const float*)d_in[9];
    const float* b2 = (const float*)d_in[10];
    const float* m2 = (const float*)d_in[11];
    const float* v2 = (const float*)d_in[12];

    float* out  = (float*)d_out;
    float* Lout = out;                  // [5,8,1,257,257]
    float* Hout = out + TOTPIX;         // [5,8,1,257,257]
    float* Pout = out + 2 * TOTPIX;     // [5,8,64,257,257]
    float* ws   = (float*)d_ws;         // 5 * WSF floats = 170 KB

    precompute_kernel<<<Sn, Cn, 0, stream>>>(w1, w2, g1, b1, m1, v1,
                                             g2, b2, m2, v2, ws);

    dim3 grid(NCHUNK, Bn, Sn);          // 65 x 8 x 5 = 2600 blocks
    fused_kernel<<<grid, TPB, 0, stream>>>(x, lp, hp, ws, Lout, Hout, Pout);
}